// Round 7
// baseline (51169.122 us; speedup 1.0000x reference)
//
#include <hip/hip_runtime.h>

// Seq2Seq LSTM (H=1024, B=64, T=512), persistent-grid, f16 MFMA, f32 state.
// Round-14 (resubmit #2; previous bench was a broker timeout, no data):
// HALVE THE BROADCAST VOLUME. Evidence r2/r10/r13: the per-step h
// broadcast over sc0sc1 loads is BYTES-bound at ~6.1 TB/s on the LLC read
// path (request-granularity changes don't move it; cache-sharing variants
// regress). Volume = NWG x 256 KB/step. So: NWG 256 -> 128, 8 units/WG.
//   - each WG = two of the old 4-unit groups (vwg = wg*2 + h, h in {0,1});
//     h store/load machinery (split-plane layout, pack shuffles) reused
//     verbatim per half. kc0 = wg>>2, q0 = wg&3, plane = h.
//   - weights: Whh0 (both halves) as f16 fills the 64 KB static LDS;
//     layer-1 Wih1/Whh1 are STREAMED per step as plain f32 L2 loads
//     (read-only, L2-resident, never invalidated) + inline f16 convert,
//     issued after the sc h-loads so LLC latency covers them.
//   - h traffic: 32 MB/step (was 64). Predict ~2x on the broadcast phase.
// Keeps: r10 master-broadcast barrier (no fences), exp2/rcp activations,
// split-plane lane-contiguous 8B coherent h loads (compiler-tracked).

#define HD 1024
#define BB 64
#define TT 512
#define NWG 128
#define NTHR 256

typedef _Float16 f16x8 __attribute__((ext_vector_type(8)));
typedef float f32x4 __attribute__((ext_vector_type(4)));
typedef unsigned long long u64;

struct KP {
  const float* seq;
  const int* mask;
  const float* Wih0;
  const float* Whh0;
  const float* b0;
  const float* Wih1;
  const float* Whh1;
  const float* b1;
  const float* fcW;
  const float* fcb;
  _Float16* h0buf;   // [2][2 planes][32768] f16: plane0=lo8B, plane1=hi8B of each 16B chunk
  _Float16* h1buf;
  float* c0buf;
  float* c1buf;
  float* predpart;   // [2][16][B]
  int* flags;        // [NWG+1]; flags[NWG] = go word
  float* out;
};

#define LOG2E 1.4426950408889634f
__device__ __forceinline__ float sigm(float x) {
  return __builtin_amdgcn_rcpf(1.0f + __builtin_amdgcn_exp2f(x * -LOG2E));
}
__device__ __forceinline__ float ftanh(float x) {
  float e = __builtin_amdgcn_exp2f(x * (2.0f * LOG2E));
  return 1.0f - 2.0f * __builtin_amdgcn_rcpf(e + 1.0f);
}

__device__ __forceinline__ u64 cload_u64(const void* p) {
  return __hip_atomic_load((const u64*)p, __ATOMIC_RELAXED, __HIP_MEMORY_SCOPE_SYSTEM);
}
__device__ __forceinline__ void cstore_u64(void* p, u64 v) {
  __hip_atomic_store((u64*)p, v, __ATOMIC_RELAXED, __HIP_MEMORY_SCOPE_SYSTEM);
}
__device__ __forceinline__ float cload_f32(const float* p) {
  return __hip_atomic_load(p, __ATOMIC_RELAXED, __HIP_MEMORY_SCOPE_SYSTEM);
}
__device__ __forceinline__ void cstore_f32(float* p, float v) {
  __hip_atomic_store(p, v, __ATOMIC_RELAXED, __HIP_MEMORY_SCOPE_SYSTEM);
}
__device__ __forceinline__ int cload_i32(const int* p) {
  return __hip_atomic_load(p, __ATOMIC_RELAXED, __HIP_MEMORY_SCOPE_SYSTEM);
}
__device__ __forceinline__ void cstore_i32(int* p, int v) {
  __hip_atomic_store(p, v, __ATOMIC_RELAXED, __HIP_MEMORY_SCOPE_SYSTEM);
}
// fragment load from split planes: lo 8B + hi 8B, both lane-contiguous.
__device__ __forceinline__ f16x8 cload_a2(const _Float16* lo, const _Float16* hi) {
  union { u64 q[2]; f16x8 v; } c;
  c.q[0] = cload_u64(lo);
  c.q[1] = cload_u64(hi);
  return c.v;
}
// layer-1 weight fragment: 8 f32 from L2 (plain, cached) -> f16x8.
__device__ __forceinline__ f16x8 wfrag(const float* s) {
  f32x4 lo = *(const f32x4*)s;
  f32x4 hi = *(const f32x4*)(s + 4);
  f16x8 v;
  v[0] = (_Float16)lo[0]; v[1] = (_Float16)lo[1];
  v[2] = (_Float16)lo[2]; v[3] = (_Float16)lo[3];
  v[4] = (_Float16)hi[0]; v[5] = (_Float16)hi[1];
  v[6] = (_Float16)hi[2]; v[7] = (_Float16)hi[3];
  return v;
}

// Master-broadcast grid barrier (r10 form). All cross-WG data via sc0sc1
// (LLC); per-wave vmcnt(0) drain before flag/go ensures store visibility.
__device__ __forceinline__ void gbar(int* flags, int epoch) {
  asm volatile("s_waitcnt vmcnt(0)" ::: "memory");
  __syncthreads();
  int* go = flags + NWG;
  if (blockIdx.x == NWG - 1) {
    if ((int)threadIdx.x < NWG - 1) {
      while (cload_i32(&flags[threadIdx.x]) < epoch)
        __builtin_amdgcn_s_sleep(1);
    }
    __syncthreads();
    if (threadIdx.x == 0) cstore_i32(go, epoch);
  } else {
    if (threadIdx.x == 0) {
      cstore_i32(&flags[blockIdx.x], epoch);
      while (cload_i32(go) < epoch)
        __builtin_amdgcn_s_sleep(1);
    }
    __syncthreads();
  }
  asm volatile("" ::: "memory");
}

__global__ void init_kernel(_Float16* h0, _Float16* h1, float* predpart, int* fe, int* fd) {
  int i = blockIdx.x * blockDim.x + threadIdx.x;
  int stride = gridDim.x * blockDim.x;
  u64* q0 = (u64*)h0;
  u64* q1 = (u64*)h1;
  for (int j = i; j < 2 * BB * HD / 4; j += stride) {
    cstore_u64(q0 + j, 0ull);
    cstore_u64(q1 + j, 0ull);
  }
  for (int j = i; j < 2 * 16 * BB; j += stride) cstore_f32(predpart + j, 0.0f);
  if (i < NWG + 1) {
    cstore_i32(fe + i, 0);
    cstore_i32(fd + i, 0);
  }
}

template <int IS_DEC>
__global__ __launch_bounds__(NTHR, 1) void seq_kernel(KP p) {
  __shared__ _Float16 ldsW0[2][32][64][8];  // 64 KB: layer-0 Whh0, both halves

  const int tid = threadIdx.x;
  const int wg = blockIdx.x;
  const int wave = tid >> 6;
  const int lane = tid & 63;
  const int n = lane & 15;
  const int q = lane >> 4;
  const int gidx = n & 3;
  const int u = n >> 2;
  const int vwg = wg * 2;             // virtual 4-unit group index (h adds 1)
  const int koff = q * 8;

  int unitGh[2], rowGh[2];
#pragma unroll
  for (int h = 0; h < 2; ++h) {
    unitGh[h] = (vwg + h) * 4 + u;
    rowGh[h] = gidx * HD + unitGh[h];
  }

  const int kc0 = wg >> 2;            // = (vwg)>>3, same for both halves
  const int q0 = wg & 3;              // = ((vwg)>>1)&3, same for both halves
  const int Lb = ((n >> 2) << 4) | (n & 3);
  const int aoffL = (wave * 2048 + lane) * 4;
  const int stbase = (((wave * 32 + kc0) << 6) + (q0 << 4) + n) * 4;

  // ---- stage layer-0 Whh0 (both halves) into LDS, fragment-swizzled ----
  for (int g = tid; g < 4096; g += NTHR) {
    int h = g >> 11;
    int gg = g & 2047;
    int kc = gg >> 6;
    int lv = gg & 63;
    int nn = lv & 15, qq = lv >> 4;
    int rG = (nn & 3) * HD + (vwg + h) * 4 + (nn >> 2);
    const float* src = p.Whh0 + rG * HD + kc * 32 + qq * 8;
#pragma unroll
    for (int j = 0; j < 8; ++j) ldsW0[h][kc][lv][j] = (_Float16)src[j];
  }

  float bias0h[2], bias1h[2], wih0h[2], fcwh[2];
#pragma unroll
  for (int h = 0; h < 2; ++h) {
    bias0h[h] = p.b0[rowGh[h]];
    bias1h[h] = p.b1[rowGh[h]];
    wih0h[h] = p.Wih0[rowGh[h]];
    fcwh[h] = p.fcW[unitGh[h]];
  }
  const float fcb = p.fcb[0];

  float c0r[2][4], c1r[2][4];
#pragma unroll
  for (int h = 0; h < 2; ++h)
#pragma unroll
    for (int r = 0; r < 4; ++r) {
      if (IS_DEC) {
        int b = wave * 16 + q * 4 + r;
        c0r[h][r] = p.c0buf[b * HD + unitGh[h]];
        c1r[h][r] = p.c1buf[b * HD + unitGh[h]];
      } else {
        c0r[h][r] = 0.0f;
        c1r[h][r] = 0.0f;
      }
    }
  __syncthreads();

  // ---- bootstrap haf = h0(prev) ----
  f16x8 haf[32];
  {
    const _Float16* hb = p.h0buf + BB * HD + aoffL;
#pragma unroll
    for (int kc = 0; kc < 32; ++kc) haf[kc] = cload_a2(hb + kc * 256, hb + 32768 + kc * 256);
  }

  int epoch = 1;
  for (int t = 0; t < TT; ++t) {
    const int wp = t & 1;
    _Float16* h0w = p.h0buf + wp * (BB * HD);
    _Float16* h1w = p.h1buf + wp * (BB * HD);
    const _Float16* h1r = p.h1buf + (1 - wp) * (BB * HD);

    // ================= layer 0 (register-carried h0, B from LDS) =========
    f32x4 l0a[2], l0b[2];
#pragma unroll
    for (int h = 0; h < 2; ++h) {
      l0a[h] = (f32x4){0.0f, 0.0f, 0.0f, 0.0f};
      l0b[h] = (f32x4){0.0f, 0.0f, 0.0f, 0.0f};
    }
#pragma unroll
    for (int h = 0; h < 2; ++h)
#pragma unroll
      for (int kc = 0; kc < 32; kc += 2) {
        l0a[h] = __builtin_amdgcn_mfma_f32_16x16x32_f16(haf[kc], *(const f16x8*)(&ldsW0[h][kc][lane][0]), l0a[h], 0, 0, 0);
        l0b[h] = __builtin_amdgcn_mfma_f32_16x16x32_f16(haf[kc + 1], *(const f16x8*)(&ldsW0[h][kc + 1][lane][0]), l0b[h], 0, 0, 0);
      }

    float xv[4];
    if (!IS_DEC) {
#pragma unroll
      for (int r = 0; r < 4; ++r) {
        int b = wave * 16 + q * 4 + r;
        xv[r] = p.seq[b * TT + t];
      }
    } else {
      if (t == 0) {
#pragma unroll
        for (int r = 0; r < 4; ++r) xv[r] = 0.0f;
      } else if (p.mask[t - 1] != 0) {
#pragma unroll
        for (int r = 0; r < 4; ++r) {
          int b = wave * 16 + q * 4 + r;
          xv[r] = p.seq[b * TT + (t - 1)];
        }
      } else {
        const float* pp = p.predpart + ((t - 1) & 1) * (16 * BB);
#pragma unroll
        for (int r = 0; r < 4; ++r) {
          int b = wave * 16 + q * 4 + r;
          float s = 0.0f;
#pragma unroll
          for (int j3 = 0; j3 < 4; ++j3) s += cload_f32(pp + (gidx * 4 + j3) * BB + b);
          s += __shfl_xor(s, 1);
          s += __shfl_xor(s, 2);
          xv[r] = s + fcb;
        }
      }
    }

    float hn0v[2][4];
#pragma unroll
    for (int h = 0; h < 2; ++h) {
      f32x4 accv = l0a[h] + l0b[h];
#pragma unroll
      for (int r = 0; r < 4; ++r) {
        float v = accv[r] + bias0h[h] + xv[r] * wih0h[h];
        float v1 = __shfl_xor(v, 1);
        float v2 = __shfl_xor(v, 2);
        float v3 = __shfl_xor(v, 3);
        float gi = (gidx == 0) ? v : (gidx == 1) ? v1 : (gidx == 2) ? v2 : v3;
        float gf = (gidx == 1) ? v : (gidx == 0) ? v1 : (gidx == 3) ? v2 : v3;
        float gg = (gidx == 2) ? v : (gidx == 3) ? v1 : (gidx == 0) ? v2 : v3;
        float go = (gidx == 3) ? v : (gidx == 2) ? v1 : (gidx == 1) ? v2 : v3;
        float cn = sigm(gf) * c0r[h][r] + sigm(gi) * ftanh(gg);
        hn0v[h][r] = sigm(go) * ftanh(cn);
        c0r[h][r] = cn;
      }
    }
#pragma unroll
    for (int h = 0; h < 2; ++h) {
      int hb0 = (int)(unsigned)__builtin_bit_cast(unsigned short, (_Float16)hn0v[h][0]);
      int hb1 = (int)(unsigned)__builtin_bit_cast(unsigned short, (_Float16)hn0v[h][1]);
      int hb2 = (int)(unsigned)__builtin_bit_cast(unsigned short, (_Float16)hn0v[h][2]);
      int hb3 = (int)(unsigned)__builtin_bit_cast(unsigned short, (_Float16)hn0v[h][3]);
      int iv = (gidx == 0) ? hb0 : (gidx == 1) ? hb1 : (gidx == 2) ? hb2 : hb3;
      int w0 = __shfl(iv, Lb);
      int w1 = __shfl(iv, Lb + 4);
      int w2 = __shfl(iv, Lb + 8);
      int w3 = __shfl(iv, Lb + 12);
      u64 lo = (unsigned)(w0 & 0xFFFF) | ((unsigned)(w1 & 0xFFFF) << 16);
      u64 hi = (unsigned)(w2 & 0xFFFF) | ((unsigned)(w3 & 0xFFFF) << 16);
      u64 pk = lo | (hi << 32);
      if (q == q0) cstore_u64(h0w + h * 32768 + stbase, pk);
    }
    gbar(p.flags, epoch++);  // barrier A (master-broadcast)

    // ================= layer 1 =================
    if (IS_DEC && wg == 0 && t > 0 && tid < BB) {
      const float* pp = p.predpart + ((t - 1) & 1) * (16 * BB);
      float s = fcb;
#pragma unroll
      for (int j2 = 0; j2 < 16; ++j2) s += cload_f32(pp + j2 * BB + tid);
      p.out[tid * TT + (t - 1)] = s;
      asm volatile("" ::: "memory");
      float* pz = p.predpart + ((t - 1) & 1) * (16 * BB);
#pragma unroll
      for (int j2 = 0; j2 < 16; ++j2) cstore_f32(pz + j2 * BB + tid, 0.0f);
    }

    // bulk-issue ALL coherent h loads (compiler-tracked sc path), then
    // stream layer-1 weights from L2 while the LLC loads drain.
    f16x8 ahf[32];
    {
      const _Float16* Ax = h0w + aoffL;
      const _Float16* Ah = h1r + aoffL;
#pragma unroll
      for (int kc = 0; kc < 32; ++kc) haf[kc] = cload_a2(Ax + kc * 256, Ax + 32768 + kc * 256);
#pragma unroll
      for (int kc = 0; kc < 32; ++kc) ahf[kc] = cload_a2(Ah + kc * 256, Ah + 32768 + kc * 256);
      asm volatile("" ::: "memory");  // pin sc loads above the weight/MFMA phase
    }
    f32x4 l1a[2], l1b[2];
#pragma unroll
    for (int h = 0; h < 2; ++h) {
      l1a[h] = (f32x4){0.0f, 0.0f, 0.0f, 0.0f};
      l1b[h] = (f32x4){0.0f, 0.0f, 0.0f, 0.0f};
    }
    {
      const float* Wa0 = p.Wih1 + rowGh[0] * HD + koff;
      const float* Wa1 = p.Wih1 + rowGh[1] * HD + koff;
#pragma unroll
      for (int kc = 0; kc < 32; kc += 2) {
        l1a[0] = __builtin_amdgcn_mfma_f32_16x16x32_f16(haf[kc], wfrag(Wa0 + kc * 32), l1a[0], 0, 0, 0);
        l1b[0] = __builtin_amdgcn_mfma_f32_16x16x32_f16(haf[kc + 1], wfrag(Wa0 + (kc + 1) * 32), l1b[0], 0, 0, 0);
        l1a[1] = __builtin_amdgcn_mfma_f32_16x16x32_f16(haf[kc], wfrag(Wa1 + kc * 32), l1a[1], 0, 0, 0);
        l1b[1] = __builtin_amdgcn_mfma_f32_16x16x32_f16(haf[kc + 1], wfrag(Wa1 + (kc + 1) * 32), l1b[1], 0, 0, 0);
      }
      const float* Wb0 = p.Whh1 + rowGh[0] * HD + koff;
      const float* Wb1 = p.Whh1 + rowGh[1] * HD + koff;
#pragma unroll
      for (int kc = 0; kc < 32; kc += 2) {
        l1a[0] = __builtin_amdgcn_mfma_f32_16x16x32_f16(ahf[kc], wfrag(Wb0 + kc * 32), l1a[0], 0, 0, 0);
        l1b[0] = __builtin_amdgcn_mfma_f32_16x16x32_f16(ahf[kc + 1], wfrag(Wb0 + (kc + 1) * 32), l1b[0], 0, 0, 0);
        l1a[1] = __builtin_amdgcn_mfma_f32_16x16x32_f16(ahf[kc], wfrag(Wb1 + kc * 32), l1a[1], 0, 0, 0);
        l1b[1] = __builtin_amdgcn_mfma_f32_16x16x32_f16(ahf[kc + 1], wfrag(Wb1 + (kc + 1) * 32), l1b[1], 0, 0, 0);
      }
    }

    float hn1v[2][4];
    float plsum[4] = {0.0f, 0.0f, 0.0f, 0.0f};
#pragma unroll
    for (int h = 0; h < 2; ++h) {
      f32x4 a2 = l1a[h] + l1b[h];
#pragma unroll
      for (int r = 0; r < 4; ++r) {
        float v = a2[r] + bias1h[h];
        float v1 = __shfl_xor(v, 1);
        float v2 = __shfl_xor(v, 2);
        float v3 = __shfl_xor(v, 3);
        float gi = (gidx == 0) ? v : (gidx == 1) ? v1 : (gidx == 2) ? v2 : v3;
        float gf = (gidx == 1) ? v : (gidx == 0) ? v1 : (gidx == 3) ? v2 : v3;
        float gg = (gidx == 2) ? v : (gidx == 3) ? v1 : (gidx == 0) ? v2 : v3;
        float go = (gidx == 3) ? v : (gidx == 2) ? v1 : (gidx == 1) ? v2 : v3;
        float cn = sigm(gf) * c1r[h][r] + sigm(gi) * ftanh(gg);
        float hn = sigm(go) * ftanh(cn);
        hn1v[h][r] = hn;
        c1r[h][r] = cn;
        if (IS_DEC) {
          float pl = (gidx == 0) ? hn * fcwh[h] : 0.0f;
          pl += __shfl_xor(pl, 1);
          pl += __shfl_xor(pl, 2);
          pl += __shfl_xor(pl, 4);
          pl += __shfl_xor(pl, 8);
          plsum[r] += pl;  // valid at lane n==0
        }
      }
    }
    if (IS_DEC && n == 0) {
#pragma unroll
      for (int r = 0; r < 4; ++r) {
        int b = wave * 16 + q * 4 + r;
        atomicAdd(p.predpart + (t & 1) * (16 * BB) + (wg >> 3) * BB + b, plsum[r]);
      }
    }
#pragma unroll
    for (int h = 0; h < 2; ++h) {
      int hb0 = (int)(unsigned)__builtin_bit_cast(unsigned short, (_Float16)hn1v[h][0]);
      int hb1 = (int)(unsigned)__builtin_bit_cast(unsigned short, (_Float16)hn1v[h][1]);
      int hb2 = (int)(unsigned)__builtin_bit_cast(unsigned short, (_Float16)hn1v[h][2]);
      int hb3 = (int)(unsigned)__builtin_bit_cast(unsigned short, (_Float16)hn1v[h][3]);
      int iv = (gidx == 0) ? hb0 : (gidx == 1) ? hb1 : (gidx == 2) ? hb2 : hb3;
      int w0 = __shfl(iv, Lb);
      int w1 = __shfl(iv, Lb + 4);
      int w2 = __shfl(iv, Lb + 8);
      int w3 = __shfl(iv, Lb + 12);
      u64 lo = (unsigned)(w0 & 0xFFFF) | ((unsigned)(w1 & 0xFFFF) << 16);
      u64 hi = (unsigned)(w2 & 0xFFFF) | ((unsigned)(w3 & 0xFFFF) << 16);
      u64 pk = lo | (hi << 32);
      if (q == q0) cstore_u64(h1w + h * 32768 + stbase, pk);
    }

    if (IS_DEC) {
      if (t == TT - 1 || p.mask[t] == 0) gbar(p.flags, epoch++);
    }
  }

  if (!IS_DEC) {
    if (gidx == 0) {
#pragma unroll
      for (int h = 0; h < 2; ++h)
#pragma unroll
        for (int r = 0; r < 4; ++r) {
          int b = wave * 16 + q * 4 + r;
          p.c0buf[b * HD + unitGh[h]] = c0r[h][r];
          p.c1buf[b * HD + unitGh[h]] = c1r[h][r];
        }
    }
  } else {
    if (wg == 0 && tid < BB) {
      const float* pp = p.predpart + ((TT - 1) & 1) * (16 * BB);
      float s = fcb;
#pragma unroll
      for (int j2 = 0; j2 < 16; ++j2) s += cload_f32(pp + j2 * BB + tid);
      p.out[tid * TT + (TT - 1)] = s;
    }
  }
}

extern "C" void kernel_launch(void* const* d_in, const int* in_sizes, int n_in,
                              void* d_out, int out_size, void* d_ws, size_t ws_size,
                              hipStream_t stream) {
  (void)in_sizes; (void)n_in; (void)out_size; (void)ws_size;
  const float* prev = (const float*)d_in[0];
  const float* nxt = (const float*)d_in[1];
  const int* mask = (const int*)d_in[2];
  const float* eWih0 = (const float*)d_in[3];
  const float* eWhh0 = (const float*)d_in[4];
  const float* eb0 = (const float*)d_in[5];
  const float* eWih1 = (const float*)d_in[6];
  const float* eWhh1 = (const float*)d_in[7];
  const float* eb1 = (const float*)d_in[8];
  const float* dWih0 = (const float*)d_in[9];
  const float* dWhh0 = (const float*)d_in[10];
  const float* db0 = (const float*)d_in[11];
  const float* dWih1 = (const float*)d_in[12];
  const float* dWhh1 = (const float*)d_in[13];
  const float* db1 = (const float*)d_in[14];
  const float* fcW = (const float*)d_in[15];
  const float* fcb = (const float*)d_in[16];

  char* w = (char*)d_ws;
  _Float16* h0buf = (_Float16*)w; w += 2 * BB * HD * 2;
  _Float16* h1buf = (_Float16*)w; w += 2 * BB * HD * 2;
  float* c0buf = (float*)w; w += BB * HD * 4;
  float* c1buf = (float*)w; w += BB * HD * 4;
  float* predpart = (float*)w; w += 2 * 16 * BB * 4;
  int* flagsE = (int*)w; w += (NWG + 1) * 4;
  int* flagsD = (int*)w; w += (NWG + 1) * 4;

  init_kernel<<<dim3(128), dim3(256), 0, stream>>>(h0buf, h1buf, predpart, flagsE, flagsD);

  KP pe;
  pe.seq = prev; pe.mask = mask;
  pe.Wih0 = eWih0; pe.Whh0 = eWhh0; pe.b0 = eb0;
  pe.Wih1 = eWih1; pe.Whh1 = eWhh1; pe.b1 = eb1;
  pe.fcW = fcW; pe.fcb = fcb;
  pe.h0buf = h0buf; pe.h1buf = h1buf;
  pe.c0buf = c0buf; pe.c1buf = c1buf;
  pe.predpart = predpart; pe.flags = flagsE;
  pe.out = (float*)d_out;
  seq_kernel<0><<<dim3(NWG), dim3(NTHR), 0, stream>>>(pe);

  KP pd = pe;
  pd.seq = nxt;
  pd.Wih0 = dWih0; pd.Whh0 = dWhh0; pd.b0 = db0;
  pd.Wih1 = dWih1; pd.Whh1 = dWhh1; pd.b1 = db1;
  pd.flags = flagsD;
  seq_kernel<1><<<dim3(NWG), dim3(NTHR), 0, stream>>>(pd);
}

// Round 9
// 12234.338 us; speedup vs baseline: 4.1824x; 4.1824x over previous
//
#include <hip/hip_runtime.h>

// Seq2Seq LSTM (H=1024, B=64, T=512), persistent-grid, f16 MFMA, f32 state.
// Round-15 (resubmit; previous bench was a broker timeout, no data):
// K-SPLIT PAIRS. r14 proved weights must stay resident (streaming
// thrashed L2 -> HBM, 5x regression). r2/r10/r13 proved the h broadcast is
// bytes-bound at ~6.1 TB/s on the MALL path. Broadcast bytes = NWG x 64batch
// x K_span x 2B x 2layers; weight bytes/WG = rows x K x 2B x 3 = 96KB for ANY
// rows<->K split. So keep NWG=256 but pair WGs (2i,2i+1): the pair owns 8
// units; each WG computes BOTH rowsets (own 4 + buddy 4 units) over HALF of
// K (even wg: K[0,512), odd: K[512,1024)). h reads per WG halve: 256->128KB.
// Pairs exchange 4KB pre-activation partials per layer via LLC with
// epoch-flag point-to-point sync (gbar's proven load/store pattern):
//   RAW: flag spin (write partial -> vmcnt drain -> flag; buddy spins).
//   WAR: single-buffered slots are safe: reader's step-t read precedes its
//        barrier-A flag; writer's step-t+1 write follows go(t).
// All weights now in LDS (96KB: Whh0/Wih1/Whh1 x 2 rowsets x K-half); the
// 128-VGPR wf0 array is gone. Ownership (units = wg*4+u), activation, pack,
// split-plane h store/load machinery identical to round-10.

#define HD 1024
#define BB 64
#define TT 512
#define NWG 256
#define NTHR 256

typedef _Float16 f16x8 __attribute__((ext_vector_type(8)));
typedef float f32x4 __attribute__((ext_vector_type(4)));
typedef unsigned long long u64;

struct KP {
  const float* seq;
  const int* mask;
  const float* Wih0;
  const float* Whh0;
  const float* b0;
  const float* Wih1;
  const float* Whh1;
  const float* b1;
  const float* fcW;
  const float* fcb;
  _Float16* h0buf;   // [2][2 planes][32768] f16: plane0=lo8B, plane1=hi8B of 16B chunks
  _Float16* h1buf;
  float* c0buf;
  float* c1buf;
  float* predpart;   // [2][16][B]
  int* flags;        // [NWG+1]; flags[NWG] = go word
  float* xch0;       // [128 pairs][2 producer][16 rows][64 batch] f32 (L0 partials)
  float* xch1;       // same for L1
  int* xf0;          // [NWG] epoch flags (L0 exchange)
  int* xf1;          // [NWG] epoch flags (L1 exchange)
  float* out;
};

#define LOG2E 1.4426950408889634f
__device__ __forceinline__ float sigm(float x) {
  return __builtin_amdgcn_rcpf(1.0f + __builtin_amdgcn_exp2f(x * -LOG2E));
}
__device__ __forceinline__ float ftanh(float x) {
  float e = __builtin_amdgcn_exp2f(x * (2.0f * LOG2E));
  return 1.0f - 2.0f * __builtin_amdgcn_rcpf(e + 1.0f);
}

__device__ __forceinline__ u64 cload_u64(const void* p) {
  return __hip_atomic_load((const u64*)p, __ATOMIC_RELAXED, __HIP_MEMORY_SCOPE_SYSTEM);
}
__device__ __forceinline__ void cstore_u64(void* p, u64 v) {
  __hip_atomic_store((u64*)p, v, __ATOMIC_RELAXED, __HIP_MEMORY_SCOPE_SYSTEM);
}
__device__ __forceinline__ float cload_f32(const float* p) {
  return __hip_atomic_load(p, __ATOMIC_RELAXED, __HIP_MEMORY_SCOPE_SYSTEM);
}
__device__ __forceinline__ void cstore_f32(float* p, float v) {
  __hip_atomic_store(p, v, __ATOMIC_RELAXED, __HIP_MEMORY_SCOPE_SYSTEM);
}
__device__ __forceinline__ int cload_i32(const int* p) {
  return __hip_atomic_load(p, __ATOMIC_RELAXED, __HIP_MEMORY_SCOPE_SYSTEM);
}
__device__ __forceinline__ void cstore_i32(int* p, int v) {
  __hip_atomic_store(p, v, __ATOMIC_RELAXED, __HIP_MEMORY_SCOPE_SYSTEM);
}
// fragment load from split planes: lo 8B + hi 8B, both lane-contiguous.
__device__ __forceinline__ f16x8 cload_a2(const _Float16* lo, const _Float16* hi) {
  union { u64 q[2]; f16x8 v; } c;
  c.q[0] = cload_u64(lo);
  c.q[1] = cload_u64(hi);
  return c.v;
}
__device__ __forceinline__ void xwrite(float* buf, f32x4 v) {
  union { f32x4 v; u64 q[2]; } c;
  c.v = v;
  cstore_u64(buf, c.q[0]);
  cstore_u64(buf + 2, c.q[1]);
}
__device__ __forceinline__ f32x4 xread(const float* buf) {
  union { f32x4 v; u64 q[2]; } c;
  c.q[0] = cload_u64(buf);
  c.q[1] = cload_u64(buf + 2);
  return c.v;
}
// pair exchange sync: drain own partial stores, flag, spin on buddy's flag.
__device__ __forceinline__ void xsync(int* xf, int slotW, int slotR, int epoch) {
  asm volatile("s_waitcnt vmcnt(0)" ::: "memory");
  __syncthreads();
  if (threadIdx.x == 0) {
    cstore_i32(xf + slotW, epoch);
    while (cload_i32(xf + slotR) < epoch)
      __builtin_amdgcn_s_sleep(1);
  }
  __syncthreads();
  asm volatile("" ::: "memory");
}

// Master-broadcast grid barrier (r10 form).
__device__ __forceinline__ void gbar(int* flags, int epoch) {
  asm volatile("s_waitcnt vmcnt(0)" ::: "memory");
  __syncthreads();
  int* go = flags + NWG;
  if (blockIdx.x == NWG - 1) {
    if ((int)threadIdx.x < NWG - 1) {
      while (cload_i32(&flags[threadIdx.x]) < epoch)
        __builtin_amdgcn_s_sleep(1);
    }
    __syncthreads();
    if (threadIdx.x == 0) cstore_i32(go, epoch);
  } else {
    if (threadIdx.x == 0) {
      cstore_i32(&flags[blockIdx.x], epoch);
      while (cload_i32(go) < epoch)
        __builtin_amdgcn_s_sleep(1);
    }
    __syncthreads();
  }
  asm volatile("" ::: "memory");
}

__global__ void init_kernel(_Float16* h0, _Float16* h1, float* predpart, int* fe, int* fd, int* xf) {
  int i = blockIdx.x * blockDim.x + threadIdx.x;
  int stride = gridDim.x * blockDim.x;
  u64* q0 = (u64*)h0;
  u64* q1 = (u64*)h1;
  for (int j = i; j < 2 * BB * HD / 4; j += stride) {
    cstore_u64(q0 + j, 0ull);
    cstore_u64(q1 + j, 0ull);
  }
  for (int j = i; j < 2 * 16 * BB; j += stride) cstore_f32(predpart + j, 0.0f);
  if (i < NWG + 1) {
    cstore_i32(fe + i, 0);
    cstore_i32(fd + i, 0);
  }
  if (i < 4 * NWG) cstore_i32(xf + i, 0);
}

template <int IS_DEC>
__global__ __launch_bounds__(NTHR, 1) void seq_kernel(KP p) {
  // 96 KB: [mat: Whh0,Wih1,Whh1][rowset][kc(16)][lane][8]
  __shared__ _Float16 ldsW[3][2][16][64][8];

  const int tid = threadIdx.x;
  const int wg = blockIdx.x;
  const int wave = tid >> 6;
  const int lane = tid & 63;
  const int n = lane & 15;
  const int q = lane >> 4;
  const int gidx = n & 3;
  const int u = n >> 2;
  const int half = wg & 1;          // K-half AND own rowset
  const int pair = wg >> 1;
  const int unitG = wg * 4 + u;     // own units: identical to r10
  const int rowG = gidx * HD + unitG;
  const int kcbase = half * 16;

  const int kc0 = wg >> 3;
  const int q0 = (wg >> 1) & 3;
  const int Lb = ((n >> 2) << 4) | (n & 3);
  // split-plane addressing, K-half window
  const int aoffH = (wave * 2048 + kcbase * 64 + lane) * 4;
  const int stoffL = half * 32768 + ((((wave * 32 + kc0) << 6) + (q0 << 4) + n) << 2);
  // exchange slot bases (floats): [pair][producer][n][batch]
  const int xwoff = (pair * 2 + half) * 1024 + n * 64 + wave * 16 + q * 4;
  const int xroff = (pair * 2 + (1 - half)) * 1024 + n * 64 + wave * 16 + q * 4;

  // ---- stage ALL weights into LDS (fragment-swizzled, rowsets x K-half) ----
  for (int g = tid; g < 6144; g += NTHR) {
    int m = g >> 11;            // 0=Whh0, 1=Wih1, 2=Whh1
    int gg = g & 2047;
    int s = gg >> 10;           // rowset
    int kc = (gg >> 6) & 15;
    int lv = gg & 63;
    int nn = lv & 15, qq = lv >> 4;
    int unit = 8 * pair + s * 4 + (nn >> 2);
    int rG = (nn & 3) * HD + unit;
    const float* src = (m == 0 ? p.Whh0 : (m == 1 ? p.Wih1 : p.Whh1)) + rG * HD + (kcbase + kc) * 32 + qq * 8;
#pragma unroll
    for (int j = 0; j < 8; ++j) ldsW[m][s][kc][lv][j] = (_Float16)src[j];
  }

  const float bias0 = p.b0[rowG];
  const float bias1 = p.b1[rowG];
  const float wih0 = p.Wih0[rowG];
  const float fcw = p.fcW[unitG];
  const float fcb = p.fcb[0];

  float c0r[4], c1r[4];
#pragma unroll
  for (int r = 0; r < 4; ++r) {
    if (IS_DEC) {
      int b = wave * 16 + q * 4 + r;
      c0r[r] = p.c0buf[b * HD + unitG];
      c1r[r] = p.c1buf[b * HD + unitG];
    } else {
      c0r[r] = 0.0f;
      c1r[r] = 0.0f;
    }
  }
  __syncthreads();

  // ---- bootstrap haf = K-half of h0(prev) ----
  f16x8 haf[16];
  {
    const _Float16* hb = p.h0buf + BB * HD + aoffH;
#pragma unroll
    for (int kc = 0; kc < 16; ++kc) haf[kc] = cload_a2(hb + kc * 256, hb + 32768 + kc * 256);
  }

  int epoch = 1;
  for (int t = 0; t < TT; ++t) {
    const int wp = t & 1;
    _Float16* h0w = p.h0buf + wp * (BB * HD);
    _Float16* h1w = p.h1buf + wp * (BB * HD);
    const _Float16* h1r = p.h1buf + (1 - wp) * (BB * HD);

    // ========== layer 0: both rowsets over own K-half ==========
    f32x4 a0 = {0.0f, 0.0f, 0.0f, 0.0f};
    f32x4 a1 = {0.0f, 0.0f, 0.0f, 0.0f};
    f32x4 b0 = {0.0f, 0.0f, 0.0f, 0.0f};
    f32x4 b1 = {0.0f, 0.0f, 0.0f, 0.0f};
#pragma unroll
    for (int kc = 0; kc < 16; kc += 2) {
      a0 = __builtin_amdgcn_mfma_f32_16x16x32_f16(haf[kc], *(const f16x8*)(&ldsW[0][0][kc][lane][0]), a0, 0, 0, 0);
      a1 = __builtin_amdgcn_mfma_f32_16x16x32_f16(haf[kc + 1], *(const f16x8*)(&ldsW[0][0][kc + 1][lane][0]), a1, 0, 0, 0);
      b0 = __builtin_amdgcn_mfma_f32_16x16x32_f16(haf[kc], *(const f16x8*)(&ldsW[0][1][kc][lane][0]), b0, 0, 0, 0);
      b1 = __builtin_amdgcn_mfma_f32_16x16x32_f16(haf[kc + 1], *(const f16x8*)(&ldsW[0][1][kc + 1][lane][0]), b1, 0, 0, 0);
    }
    f32x4 part0 = a0 + a1;   // rowset 0 partial (own K-half)
    f32x4 part1 = b0 + b1;   // rowset 1 partial

    float xv[4];
    if (!IS_DEC) {
#pragma unroll
      for (int r = 0; r < 4; ++r) {
        int b = wave * 16 + q * 4 + r;
        xv[r] = p.seq[b * TT + t];
      }
    } else {
      if (t == 0) {
#pragma unroll
        for (int r = 0; r < 4; ++r) xv[r] = 0.0f;
      } else if (p.mask[t - 1] != 0) {
#pragma unroll
        for (int r = 0; r < 4; ++r) {
          int b = wave * 16 + q * 4 + r;
          xv[r] = p.seq[b * TT + (t - 1)];
        }
      } else {
        const float* pp = p.predpart + ((t - 1) & 1) * (16 * BB);
#pragma unroll
        for (int r = 0; r < 4; ++r) {
          int b = wave * 16 + q * 4 + r;
          float s = 0.0f;
#pragma unroll
          for (int j3 = 0; j3 < 4; ++j3) s += cload_f32(pp + (gidx * 4 + j3) * BB + b);
          s += __shfl_xor(s, 1);
          s += __shfl_xor(s, 2);
          xv[r] = s + fcb;
        }
      }
    }

    // exchange: write buddy's rowset partial, sync, read buddy's partial of ours
    xwrite(p.xch0 + xwoff, half ? part0 : part1);
    xsync(p.xf0, wg, wg ^ 1, t + 1);
    f32x4 acc = (half ? part1 : part0) + xread(p.xch0 + xroff);

    float hn0[4];
#pragma unroll
    for (int r = 0; r < 4; ++r) {
      float v = acc[r] + bias0 + xv[r] * wih0;
      float v1 = __shfl_xor(v, 1);
      float v2 = __shfl_xor(v, 2);
      float v3 = __shfl_xor(v, 3);
      float gi = (gidx == 0) ? v : (gidx == 1) ? v1 : (gidx == 2) ? v2 : v3;
      float gf = (gidx == 1) ? v : (gidx == 0) ? v1 : (gidx == 3) ? v2 : v3;
      float gg = (gidx == 2) ? v : (gidx == 3) ? v1 : (gidx == 0) ? v2 : v3;
      float go = (gidx == 3) ? v : (gidx == 2) ? v1 : (gidx == 1) ? v2 : v3;
      float cn = sigm(gf) * c0r[r] + sigm(gi) * ftanh(gg);
      hn0[r] = sigm(go) * ftanh(cn);
      c0r[r] = cn;
    }
    {
      int hb0 = (int)(unsigned)__builtin_bit_cast(unsigned short, (_Float16)hn0[0]);
      int hb1 = (int)(unsigned)__builtin_bit_cast(unsigned short, (_Float16)hn0[1]);
      int hb2 = (int)(unsigned)__builtin_bit_cast(unsigned short, (_Float16)hn0[2]);
      int hb3 = (int)(unsigned)__builtin_bit_cast(unsigned short, (_Float16)hn0[3]);
      int iv = (gidx == 0) ? hb0 : (gidx == 1) ? hb1 : (gidx == 2) ? hb2 : hb3;
      int w0 = __shfl(iv, Lb);
      int w1 = __shfl(iv, Lb + 4);
      int w2 = __shfl(iv, Lb + 8);
      int w3 = __shfl(iv, Lb + 12);
      u64 lo = (unsigned)(w0 & 0xFFFF) | ((unsigned)(w1 & 0xFFFF) << 16);
      u64 hi = (unsigned)(w2 & 0xFFFF) | ((unsigned)(w3 & 0xFFFF) << 16);
      u64 pk = lo | (hi << 32);
      if (q == q0) cstore_u64(h0w + stoffL, pk);
    }
    gbar(p.flags, epoch++);  // barrier A

    // ========== layer 1 ==========
    if (IS_DEC && wg == 0 && t > 0 && tid < BB) {
      const float* pp = p.predpart + ((t - 1) & 1) * (16 * BB);
      float s = fcb;
#pragma unroll
      for (int j2 = 0; j2 < 16; ++j2) s += cload_f32(pp + j2 * BB + tid);
      p.out[tid * TT + (t - 1)] = s;
      asm volatile("" ::: "memory");
      float* pz = p.predpart + ((t - 1) & 1) * (16 * BB);
#pragma unroll
      for (int j2 = 0; j2 < 16; ++j2) cstore_f32(pz + j2 * BB + tid, 0.0f);
    }

    // bulk-issue K-half loads of h0new and h1prev, then MFMA.
    f16x8 ahf[16];
    {
      const _Float16* Ax = h0w + aoffH;
      const _Float16* Ah = h1r + aoffH;
#pragma unroll
      for (int kc = 0; kc < 16; ++kc) haf[kc] = cload_a2(Ax + kc * 256, Ax + 32768 + kc * 256);
#pragma unroll
      for (int kc = 0; kc < 16; ++kc) ahf[kc] = cload_a2(Ah + kc * 256, Ah + 32768 + kc * 256);
      asm volatile("" ::: "memory");  // pin loads above the MFMA phase
    }
    f32x4 q0a = {0.0f, 0.0f, 0.0f, 0.0f};
    f32x4 q0b = {0.0f, 0.0f, 0.0f, 0.0f};
    f32x4 q1a = {0.0f, 0.0f, 0.0f, 0.0f};
    f32x4 q1b = {0.0f, 0.0f, 0.0f, 0.0f};
#pragma unroll
    for (int kc = 0; kc < 16; ++kc) {
      q0a = __builtin_amdgcn_mfma_f32_16x16x32_f16(haf[kc], *(const f16x8*)(&ldsW[1][0][kc][lane][0]), q0a, 0, 0, 0);
      q0b = __builtin_amdgcn_mfma_f32_16x16x32_f16(ahf[kc], *(const f16x8*)(&ldsW[2][0][kc][lane][0]), q0b, 0, 0, 0);
      q1a = __builtin_amdgcn_mfma_f32_16x16x32_f16(haf[kc], *(const f16x8*)(&ldsW[1][1][kc][lane][0]), q1a, 0, 0, 0);
      q1b = __builtin_amdgcn_mfma_f32_16x16x32_f16(ahf[kc], *(const f16x8*)(&ldsW[2][1][kc][lane][0]), q1b, 0, 0, 0);
    }
    f32x4 p1s0 = q0a + q0b;
    f32x4 p1s1 = q1a + q1b;

    xwrite(p.xch1 + xwoff, half ? p1s0 : p1s1);
    xsync(p.xf1, wg, wg ^ 1, t + 1);
    f32x4 acc2 = (half ? p1s1 : p1s0) + xread(p.xch1 + xroff);

    float hn1[4];
#pragma unroll
    for (int r = 0; r < 4; ++r) {
      float v = acc2[r] + bias1;
      float v1 = __shfl_xor(v, 1);
      float v2 = __shfl_xor(v, 2);
      float v3 = __shfl_xor(v, 3);
      float gi = (gidx == 0) ? v : (gidx == 1) ? v1 : (gidx == 2) ? v2 : v3;
      float gf = (gidx == 1) ? v : (gidx == 0) ? v1 : (gidx == 3) ? v2 : v3;
      float gg = (gidx == 2) ? v : (gidx == 3) ? v1 : (gidx == 0) ? v2 : v3;
      float go = (gidx == 3) ? v : (gidx == 2) ? v1 : (gidx == 1) ? v2 : v3;
      float cn = sigm(gf) * c1r[r] + sigm(gi) * ftanh(gg);
      float hn = sigm(go) * ftanh(cn);
      hn1[r] = hn;
      c1r[r] = cn;
      if (IS_DEC) {
        float pl = (gidx == 0) ? hn * fcw : 0.0f;
        pl += __shfl_xor(pl, 1);
        pl += __shfl_xor(pl, 2);
        pl += __shfl_xor(pl, 4);
        pl += __shfl_xor(pl, 8);
        if (n == 0) {
          int b = wave * 16 + q * 4 + r;
          atomicAdd(p.predpart + (t & 1) * (16 * BB) + (wg >> 4) * BB + b, pl);
        }
      }
    }
    {
      int hb0 = (int)(unsigned)__builtin_bit_cast(unsigned short, (_Float16)hn1[0]);
      int hb1 = (int)(unsigned)__builtin_bit_cast(unsigned short, (_Float16)hn1[1]);
      int hb2 = (int)(unsigned)__builtin_bit_cast(unsigned short, (_Float16)hn1[2]);
      int hb3 = (int)(unsigned)__builtin_bit_cast(unsigned short, (_Float16)hn1[3]);
      int iv = (gidx == 0) ? hb0 : (gidx == 1) ? hb1 : (gidx == 2) ? hb2 : hb3;
      int w0 = __shfl(iv, Lb);
      int w1 = __shfl(iv, Lb + 4);
      int w2 = __shfl(iv, Lb + 8);
      int w3 = __shfl(iv, Lb + 12);
      u64 lo = (unsigned)(w0 & 0xFFFF) | ((unsigned)(w1 & 0xFFFF) << 16);
      u64 hi = (unsigned)(w2 & 0xFFFF) | ((unsigned)(w3 & 0xFFFF) << 16);
      u64 pk = lo | (hi << 32);
      if (q == q0) cstore_u64(h1w + stoffL, pk);
    }

    if (IS_DEC) {
      if (t == TT - 1 || p.mask[t] == 0) gbar(p.flags, epoch++);
    }
  }

  if (!IS_DEC) {
    if (gidx == 0) {
#pragma unroll
      for (int r = 0; r < 4; ++r) {
        int b = wave * 16 + q * 4 + r;
        p.c0buf[b * HD + unitG] = c0r[r];
        p.c1buf[b * HD + unitG] = c1r[r];
      }
    }
  } else {
    if (wg == 0 && tid < BB) {
      const float* pp = p.predpart + ((TT - 1) & 1) * (16 * BB);
      float s = fcb;
#pragma unroll
      for (int j2 = 0; j2 < 16; ++j2) s += cload_f32(pp + j2 * BB + tid);
      p.out[tid * TT + (TT - 1)] = s;
    }
  }
}

extern "C" void kernel_launch(void* const* d_in, const int* in_sizes, int n_in,
                              void* d_out, int out_size, void* d_ws, size_t ws_size,
                              hipStream_t stream) {
  (void)in_sizes; (void)n_in; (void)out_size; (void)ws_size;
  const float* prev = (const float*)d_in[0];
  const float* nxt = (const float*)d_in[1];
  const int* mask = (const int*)d_in[2];
  const float* eWih0 = (const float*)d_in[3];
  const float* eWhh0 = (const float*)d_in[4];
  const float* eb0 = (const float*)d_in[5];
  const float* eWih1 = (const float*)d_in[6];
  const float* eWhh1 = (const float*)d_in[7];
  const float* eb1 = (const float*)d_in[8];
  const float* dWih0 = (const float*)d_in[9];
  const float* dWhh0 = (const float*)d_in[10];
  const float* db0 = (const float*)d_in[11];
  const float* dWih1 = (const float*)d_in[12];
  const float* dWhh1 = (const float*)d_in[13];
  const float* db1 = (const float*)d_in[14];
  const float* fcW = (const float*)d_in[15];
  const float* fcb = (const float*)d_in[16];

  char* w = (char*)d_ws;
  _Float16* h0buf = (_Float16*)w; w += 2 * BB * HD * 2;
  _Float16* h1buf = (_Float16*)w; w += 2 * BB * HD * 2;
  float* c0buf = (float*)w; w += BB * HD * 4;
  float* c1buf = (float*)w; w += BB * HD * 4;
  float* predpart = (float*)w; w += 2 * 16 * BB * 4;
  int* flagsE = (int*)w; w += (NWG + 1) * 4;
  int* flagsD = (int*)w; w += (NWG + 1) * 4;
  float* xch0 = (float*)w; w += 128 * 2 * 16 * 64 * 4;   // 1 MB
  float* xch1 = (float*)w; w += 128 * 2 * 16 * 64 * 4;   // 1 MB
  int* xfAll = (int*)w; w += 4 * NWG * 4;                // xf0E,xf1E,xf0D,xf1D
  int* xf0E = xfAll;
  int* xf1E = xfAll + NWG;
  int* xf0D = xfAll + 2 * NWG;
  int* xf1D = xfAll + 3 * NWG;

  init_kernel<<<dim3(128), dim3(256), 0, stream>>>(h0buf, h1buf, predpart, flagsE, flagsD, xfAll);

  KP pe;
  pe.seq = prev; pe.mask = mask;
  pe.Wih0 = eWih0; pe.Whh0 = eWhh0; pe.b0 = eb0;
  pe.Wih1 = eWih1; pe.Whh1 = eWhh1; pe.b1 = eb1;
  pe.fcW = fcW; pe.fcb = fcb;
  pe.h0buf = h0buf; pe.h1buf = h1buf;
  pe.c0buf = c0buf; pe.c1buf = c1buf;
  pe.predpart = predpart; pe.flags = flagsE;
  pe.xch0 = xch0; pe.xch1 = xch1; pe.xf0 = xf0E; pe.xf1 = xf1E;
  pe.out = (float*)d_out;
  seq_kernel<0><<<dim3(NWG), dim3(NTHR), 0, stream>>>(pe);

  KP pd = pe;
  pd.seq = nxt;
  pd.Wih0 = dWih0; pd.Whh0 = dWhh0; pd.b0 = db0;
  pd.Wih1 = dWih1; pd.Whh1 = dWhh1; pd.b1 = db1;
  pd.flags = flagsD;
  pd.xf0 = xf0D; pd.xf1 = xf1D;
  seq_kernel<1><<<dim3(NWG), dim3(NTHR), 0, stream>>>(pd);
}